// Round 2
// baseline (1257.312 us; speedup 1.0000x reference)
//
#include <hip/hip_runtime.h>

// RNN_64072322122514: B=4096, T=2048, F=8, H=32, O=8 Elman RNN (all fp32 —
// per reference dtypes; R1's NaN came from misreading fp32 buffers as bf16).
//   xp = x @ W_ih^T + b_ih + b_hh;  h_t = tanh(xp_t + h_{t-1} @ W_hh^T)
//   y = h_T @ W_out^T + b_out
//
// 4096 independent sequential chains => vector-ALU design (MFMA would cap at
// 256 waves = 1/CU and serialize on the recurrence latency):
//   - 16 lanes per batch row: lane p owns h-dims {2p,2p+1} and the matching
//     2 rows of W_hh (64 fp32 VGPRs) + W_ih (16) in registers all-kernel.
//   - 4 rows/wave, 4 waves/block (256 thr), grid=256 -> 1 block/CU,
//     1024 waves = 1 wave/SIMD chip-wide.
//   - per-step h all-to-all via 32 ds_swizzle (BitMode and=0x10 | or=j:
//     new_lane=(lane&0x10)|j, broadcast of team-lane j within each 16-lane
//     team; one swizzle serves all 4 rows of the wave).
//   - h carried in fp32 (no per-step rounding noise into the recurrence).

static constexpr int T_STEPS = 2048;
static constexpr int FDIM    = 8;
static constexpr int HDIM    = 32;
static constexpr int ODIM    = 8;
static constexpr int ROWS_PER_BLOCK = 16;

// tanh(x) = 1 - 2/(exp2(2*log2e*x) + 1); v_exp_f32/v_rcp_f32 are ~1 ulp.
// Saturates correctly: x->+inf => e=inf, rcp=0 => 1; x->-inf => e=0 => -1.
__device__ __forceinline__ float tanh_fast(float x) {
    float e = __builtin_amdgcn_exp2f(x * 2.8853900817779268f);
    return 1.0f - 2.0f * __builtin_amdgcn_rcpf(e + 1.0f);
}

__global__ __launch_bounds__(256, 1) void rnn_scan_kernel(
    const float* __restrict__ x,      // [B, T, F]
    const float* __restrict__ W_ih,   // [H, F]
    const float* __restrict__ W_hh,   // [H, H]
    const float* __restrict__ b_ih,   // [H]
    const float* __restrict__ b_hh,   // [H]
    const float* __restrict__ W_out,  // [O, H]
    const float* __restrict__ b_out,  // [O]
    float* __restrict__ out)          // [1, B, O]
{
    const int tid = threadIdx.x;
    const int p   = tid & 15;        // rank within 16-lane team
    const int row = tid >> 4;        // 0..15 within block
    const long long b = (long long)blockIdx.x * ROWS_PER_BLOCK + row;

    const int i0 = 2 * p, i1 = 2 * p + 1;

    // ---- one-time: this lane's weight rows into registers ----
    float wh0[HDIM], wh1[HDIM];
#pragma unroll
    for (int j = 0; j < HDIM; ++j) {
        wh0[j] = W_hh[i0 * HDIM + j];
        wh1[j] = W_hh[i1 * HDIM + j];
    }
    float wi0[FDIM], wi1[FDIM];
#pragma unroll
    for (int f = 0; f < FDIM; ++f) {
        wi0[f] = W_ih[i0 * FDIM + f];
        wi1[f] = W_ih[i1 * FDIM + f];
    }
    const float bias0 = b_ih[i0] + b_hh[i0];
    const float bias1 = b_ih[i1] + b_hh[i1];

    // ---- sequential scan over T ----
    const float4* xq = reinterpret_cast<const float4*>(x + (size_t)b * T_STEPS * FDIM);
    float h0 = 0.0f, h1 = 0.0f;

    for (int t = 0; t < T_STEPS; ++t) {
        // x[b,t,0:8] = 32 B, same address across the 16-lane team (HW bcast)
        const float4 xa = xq[2 * t];
        const float4 xb = xq[2 * t + 1];
        const float xv[FDIM] = {xa.x, xa.y, xa.z, xa.w, xb.x, xb.y, xb.z, xb.w};

        float a0 = bias0, a1 = bias1;
#pragma unroll
        for (int f = 0; f < FDIM; ++f) {
            a0 += wi0[f] * xv[f];
            a1 += wi1[f] * xv[f];
        }

        // gather the team's 32 h values: team-lane j holds (h[2j], h[2j+1]).
        // BitMode swizzle offset = (or=j)<<5 | (and=0x10): new=(lane&0x10)|j.
        float hg[HDIM];
#define GATH(j)                                                                              \
        hg[2*(j)]   = __int_as_float(__builtin_amdgcn_ds_swizzle(__float_as_int(h0),         \
                                     (((j) << 5) | 0x10)));                                  \
        hg[2*(j)+1] = __int_as_float(__builtin_amdgcn_ds_swizzle(__float_as_int(h1),         \
                                     (((j) << 5) | 0x10)));
        GATH(0)  GATH(1)  GATH(2)  GATH(3)
        GATH(4)  GATH(5)  GATH(6)  GATH(7)
        GATH(8)  GATH(9)  GATH(10) GATH(11)
        GATH(12) GATH(13) GATH(14) GATH(15)
#undef GATH

#pragma unroll
        for (int j = 0; j < HDIM; ++j) {
            a0 += wh0[j] * hg[j];
            a1 += wh1[j] * hg[j];
        }

        h0 = tanh_fast(a0);
        h1 = tanh_fast(a1);
    }

    // ---- epilogue: y = h @ W_out^T + b_out (tiny; via LDS) ----
    __shared__ float hb[ROWS_PER_BLOCK][HDIM];
    hb[row][i0] = h0;
    hb[row][i1] = h1;
    __syncthreads();

    if (tid < ROWS_PER_BLOCK * ODIM) {   // 128 threads
        const int r = tid >> 3;
        const int o = tid & 7;
        float acc = b_out[o];
#pragma unroll
        for (int j = 0; j < HDIM; ++j)
            acc += hb[r][j] * W_out[o * HDIM + j];
        const long long bb = (long long)blockIdx.x * ROWS_PER_BLOCK + r;
        out[bb * ODIM + o] = acc;
    }
}

extern "C" void kernel_launch(void* const* d_in, const int* in_sizes, int n_in,
                              void* d_out, int out_size, void* d_ws, size_t ws_size,
                              hipStream_t stream) {
    const float* x     = (const float*)d_in[0];
    const float* W_ih  = (const float*)d_in[1];
    const float* W_hh  = (const float*)d_in[2];
    const float* b_ih  = (const float*)d_in[3];
    const float* b_hh  = (const float*)d_in[4];
    const float* W_out = (const float*)d_in[5];
    const float* b_out = (const float*)d_in[6];

    const int B = in_sizes[0] / (T_STEPS * FDIM);   // 4096
    const int grid = B / ROWS_PER_BLOCK;            // 256 blocks -> 1/CU

    rnn_scan_kernel<<<grid, 256, 0, stream>>>(
        x, W_ih, W_hh, b_ih, b_hh, W_out, b_out, (float*)d_out);
}

// Round 3
// 1016.672 us; speedup vs baseline: 1.2367x; 1.2367x over previous
//
#include <hip/hip_runtime.h>

// RNN_64072322122514: B=4096, T=2048, F=8, H=32, O=8 Elman RNN, all fp32.
//   h_t = tanh(x_t @ W_ih^T + b_ih + b_hh + h_{t-1} @ W_hh^T);  y = h_T @ W_out^T + b_out
//
// R2 post-mortem (1047 us, VALUBusy 35%, Occ 12%, VGPR 64): latency-bound at
// 1 wave/SIMD; compiler did NOT keep the 140-float working set in registers
// (VGPR=64 => per-step reloads); serial 32-FMA accumulation chain; unprefetched
// x load on the critical path. This version:
//   - 32 lanes per batch row (lane q owns h-dim q, one 32-float W_hh row in
//     regs). 4096 rows x 32 lanes = 2048 waves = 2 waves/SIMD (Occ 25%).
//   - 4 independent accumulators -> dot-product dep tree depth 8, not 32
//     (source-level reassociation; no fast-math flag needed).
//   - x prefetched one 4-step group ahead (8 x float4 ping-pong) so the
//     global-load latency sits behind a whole group of compute.
//   - h broadcast via ds_swizzle BitMode (offset j<<5: new_lane = j within
//     each 32-lane group == the team) on the otherwise-idle LDS pipe.
//   - h carried in fp32; tanh via v_exp_f32/v_rcp_f32 (~1 ulp, saturating).

static constexpr int T_STEPS = 2048;
static constexpr int FDIM    = 8;
static constexpr int HDIM    = 32;
static constexpr int ODIM    = 8;
static constexpr int ROWS_PER_BLOCK = 8;   // 8 teams of 32 lanes = 256 threads
static constexpr int GROUP   = 4;          // steps per prefetch group
static constexpr int NGROUP  = T_STEPS / GROUP;

__device__ __forceinline__ float tanh_fast(float x) {
    float e = __builtin_amdgcn_exp2f(x * 2.8853900817779268f);
    return 1.0f - 2.0f * __builtin_amdgcn_rcpf(e + 1.0f);
}

__global__ __launch_bounds__(256, 2) void rnn_scan_kernel(
    const float* __restrict__ x,      // [B, T, F]
    const float* __restrict__ W_ih,   // [H, F]
    const float* __restrict__ W_hh,   // [H, H]
    const float* __restrict__ b_ih,   // [H]
    const float* __restrict__ b_hh,   // [H]
    const float* __restrict__ W_out,  // [O, H]
    const float* __restrict__ b_out,  // [O]
    float* __restrict__ out)          // [1, B, O]
{
    const int tid  = threadIdx.x;
    const int q    = tid & 31;        // h-dim owned by this lane
    const int team = tid >> 5;        // 0..7 within block
    const long long b = (long long)blockIdx.x * ROWS_PER_BLOCK + team;

    // ---- resident weights: one W_hh row + one W_ih row per lane ----
    float wh[HDIM];
#pragma unroll
    for (int j = 0; j < HDIM; ++j) wh[j] = W_hh[q * HDIM + j];
    float wi[FDIM];
#pragma unroll
    for (int f = 0; f < FDIM; ++f) wi[f] = W_ih[q * FDIM + f];
    const float bias = b_ih[q] + b_hh[q];

    // ---- scan with 4-step group prefetch ----
    const float4* xq = reinterpret_cast<const float4*>(x + (size_t)b * T_STEPS * FDIM);
    float4 cur[2 * GROUP];
#pragma unroll
    for (int k = 0; k < 2 * GROUP; ++k) cur[k] = xq[k];

    float h = 0.0f;

    for (int g = 0; g < NGROUP; ++g) {
        // issue next group's loads now; consumed only after this group's compute
        const float4* nsrc = xq + (size_t)((g + 1 < NGROUP) ? (g + 1) : g) * (2 * GROUP);
        float4 nxt[2 * GROUP];
#pragma unroll
        for (int k = 0; k < 2 * GROUP; ++k) nxt[k] = nsrc[k];

#pragma unroll
        for (int s = 0; s < GROUP; ++s) {
            const float4 xa = cur[2 * s];
            const float4 xb = cur[2 * s + 1];

            // 4 independent accumulator chains (tree reassociation)
            float c0 = bias, c1 = 0.0f, c2 = 0.0f, c3 = 0.0f;
            c0 = fmaf(wi[0], xa.x, c0);  c1 = fmaf(wi[1], xa.y, c1);
            c2 = fmaf(wi[2], xa.z, c2);  c3 = fmaf(wi[3], xa.w, c3);
            c0 = fmaf(wi[4], xb.x, c0);  c1 = fmaf(wi[5], xb.y, c1);
            c2 = fmaf(wi[6], xb.z, c2);  c3 = fmaf(wi[7], xb.w, c3);

            // broadcast each team-lane j's h to the whole 32-lane team and FMA.
            // BitMode swizzle offset = (or=j)<<5, and=0: new_lane = j (per 32-group).
#define GJ(j, acc)                                                                       \
            { float hj = __int_as_float(__builtin_amdgcn_ds_swizzle(                     \
                             __float_as_int(h), ((j) << 5)));                            \
              acc = fmaf(wh[j], hj, acc); }
            GJ(0,  c0) GJ(1,  c1) GJ(2,  c2) GJ(3,  c3)
            GJ(4,  c0) GJ(5,  c1) GJ(6,  c2) GJ(7,  c3)
            GJ(8,  c0) GJ(9,  c1) GJ(10, c2) GJ(11, c3)
            GJ(12, c0) GJ(13, c1) GJ(14, c2) GJ(15, c3)
            GJ(16, c0) GJ(17, c1) GJ(18, c2) GJ(19, c3)
            GJ(20, c0) GJ(21, c1) GJ(22, c2) GJ(23, c3)
            GJ(24, c0) GJ(25, c1) GJ(26, c2) GJ(27, c3)
            GJ(28, c0) GJ(29, c1) GJ(30, c2) GJ(31, c3)
#undef GJ

            h = tanh_fast((c0 + c1) + (c2 + c3));
        }

#pragma unroll
        for (int k = 0; k < 2 * GROUP; ++k) cur[k] = nxt[k];
    }

    // ---- epilogue: y = h @ W_out^T + b_out ----
    __shared__ float hb[ROWS_PER_BLOCK][HDIM];
    hb[team][q] = h;
    __syncthreads();

    if (tid < ROWS_PER_BLOCK * ODIM) {   // 64 threads
        const int r = tid >> 3;
        const int o = tid & 7;
        float acc = b_out[o];
#pragma unroll
        for (int j = 0; j < HDIM; ++j)
            acc = fmaf(hb[r][j], W_out[o * HDIM + j], acc);
        const long long bb = (long long)blockIdx.x * ROWS_PER_BLOCK + r;
        out[bb * ODIM + o] = acc;
    }
}

extern "C" void kernel_launch(void* const* d_in, const int* in_sizes, int n_in,
                              void* d_out, int out_size, void* d_ws, size_t ws_size,
                              hipStream_t stream) {
    const float* x     = (const float*)d_in[0];
    const float* W_ih  = (const float*)d_in[1];
    const float* W_hh  = (const float*)d_in[2];
    const float* b_ih  = (const float*)d_in[3];
    const float* b_hh  = (const float*)d_in[4];
    const float* W_out = (const float*)d_in[5];
    const float* b_out = (const float*)d_in[6];

    const int B = in_sizes[0] / (T_STEPS * FDIM);   // 4096
    const int grid = B / ROWS_PER_BLOCK;            // 512 blocks = 2/CU

    rnn_scan_kernel<<<grid, 256, 0, stream>>>(
        x, W_ih, W_hh, b_ih, b_hh, W_out, b_out, (float*)d_out);
}

// Round 4
// 742.668 us; speedup vs baseline: 1.6930x; 1.3689x over previous
//
#include <hip/hip_runtime.h>

// RNN_64072322122514: B=4096, T=2048, F=8, H=32, O=8 Elman RNN, all fp32.
//   h_t = tanh(x_t @ W_ih^T + b_ih + b_hh + h_{t-1} @ W_hh^T);  y = h_T @ W_out^T + b_out
//
// R3 post-mortem (1017 us, VALUBusy 52%, Occ 22.5%, VGPR 56): latency-bound at
// 2 waves/SIMD; compiler sank the prefetch loads to their uses (VGPR=56 proves
// the 110-float working set was never resident). R4 restructure:
//   - ONE wave per batch row, K-split across the two 32-lane halves:
//     lane=(q=h-dim 0..31, half=k-range). 4096 waves = 4/SIMD (Occ ~50%).
//   - h broadcast via per-wave LDS row: 1 ds_write_b32 + 4 ds_read_b128 per
//     step (same-address b128 reads broadcast; wave-synchronous, in-order LDS
//     pipe => NO barriers). 6 DS ops/step vs 32 swizzles before.
//   - cross-half dot-product reduce: one wave-wide ds_bpermute (lane^32).
//   - x prefetch 1 group (4 steps) ahead; loads pinned above an
//     asm volatile("" ::: "memory") clobber so they cannot sink to use.
//   - weights pre-scaled by 2*log2e => tanh = 1 - 2*rcp(exp2(s)+1), no mul.
//   - float2 ext-vector FMAs to invite v_pk_fma_f32.

typedef float v2f __attribute__((ext_vector_type(2)));

static constexpr int T_STEPS = 2048;
static constexpr int FDIM    = 8;
static constexpr int HDIM    = 32;
static constexpr int ODIM    = 8;
static constexpr int WAVES_PER_BLOCK = 4;   // 1 row per wave
static constexpr int GROUP   = 4;
static constexpr int NGROUP  = T_STEPS / GROUP;

__global__ __launch_bounds__(256, 4) void rnn_scan_kernel(
    const float* __restrict__ x,      // [B, T, F]
    const float* __restrict__ W_ih,   // [H, F]
    const float* __restrict__ W_hh,   // [H, H]
    const float* __restrict__ b_ih,   // [H]
    const float* __restrict__ b_hh,   // [H]
    const float* __restrict__ W_out,  // [O, H]
    const float* __restrict__ b_out,  // [O]
    float* __restrict__ out)          // [1, B, O]
{
    const float K = 2.8853900817779268f;  // 2*log2(e)
    const int tid  = threadIdx.x;
    const int lane = tid & 63;
    const int wave = tid >> 6;
    const int q    = lane & 31;   // h-dim owned by this lane
    const int half = lane >> 5;   // k-range [16*half, 16*half+16)
    const long long b = (long long)blockIdx.x * WAVES_PER_BLOCK + wave;

    __shared__ float hsh[WAVES_PER_BLOCK][HDIM];   // 512 B

    // ---- resident weights, pre-scaled by K ----
    v2f wh2[8];
    const float* whr = W_hh + q * HDIM + half * 16;
#pragma unroll
    for (int i = 0; i < 8; ++i) {
        v2f w; w[0] = whr[2 * i] * K; w[1] = whr[2 * i + 1] * K; wh2[i] = w;
    }
    v2f wi2[2];
    const float* wir = W_ih + q * FDIM + half * 4;
    {
        v2f w; w[0] = wir[0] * K; w[1] = wir[1] * K; wi2[0] = w;
        w[0] = wir[2] * K; w[1] = wir[3] * K; wi2[1] = w;
    }
    const float bias = half ? 0.0f : (b_ih[q] + b_hh[q]) * K;  // once per row

    const int paddr = ((lane ^ 32) & 63) * 4;   // bpermute partner byte-index

    hsh[wave][q] = 0.0f;   // h_0 = 0 (both halves write same value: benign)

    const float4* xq = reinterpret_cast<const float4*>(x + (size_t)b * T_STEPS * FDIM);
    const float4* hp = reinterpret_cast<const float4*>(&hsh[wave][half * 16]);
    float* hw = &hsh[wave][q];

    // x[t] for this lane = xq[2*t + half] (its half's 4 features)
    float4 cx0 = xq[0 + half], cx1 = xq[2 + half],
           cx2 = xq[4 + half], cx3 = xq[6 + half];

    for (int g = 0; g < NGROUP; ++g) {
        const int nb = ((g + 1 < NGROUP) ? (g + 1) : g) * (2 * GROUP);
        float4 nx0 = xq[nb + 0 + half], nx1 = xq[nb + 2 + half],
               nx2 = xq[nb + 4 + half], nx3 = xq[nb + 6 + half];
        // loads above may not sink past this clobber: prefetch distance >= 1 group
        asm volatile("" ::: "memory");

#define STEP(xr)                                                               \
        {                                                                      \
            float4 g0 = hp[0], g1 = hp[1], g2 = hp[2], g3 = hp[3];             \
            v2f a0; a0[0] = bias; a0[1] = 0.0f;                                \
            v2f a1; a1[0] = 0.0f; a1[1] = 0.0f;                                \
            v2f t2;                                                            \
            t2[0] = xr.x; t2[1] = xr.y;  a0 += wi2[0] * t2;                    \
            t2[0] = xr.z; t2[1] = xr.w;  a1 += wi2[1] * t2;                    \
            t2[0] = g0.x; t2[1] = g0.y;  a0 += wh2[0] * t2;                    \
            t2[0] = g0.z; t2[1] = g0.w;  a1 += wh2[1] * t2;                    \
            t2[0] = g1.x; t2[1] = g1.y;  a0 += wh2[2] * t2;                    \
            t2[0] = g1.z; t2[1] = g1.w;  a1 += wh2[3] * t2;                    \
            t2[0] = g2.x; t2[1] = g2.y;  a0 += wh2[4] * t2;                    \
            t2[0] = g2.z; t2[1] = g2.w;  a1 += wh2[5] * t2;                    \
            t2[0] = g3.x; t2[1] = g3.y;  a0 += wh2[6] * t2;                    \
            t2[0] = g3.z; t2[1] = g3.w;  a1 += wh2[7] * t2;                    \
            v2f as = a0 + a1;                                                  \
            float part = as[0] + as[1];                                        \
            float oth  = __int_as_float(__builtin_amdgcn_ds_bpermute(          \
                             paddr, __float_as_int(part)));                    \
            float s = part + oth;                                              \
            float e = __builtin_amdgcn_exp2f(s);                               \
            float r = __builtin_amdgcn_rcpf(e + 1.0f);                         \
            *hw = fmaf(-2.0f, r, 1.0f);                                        \
        }

        STEP(cx0) STEP(cx1) STEP(cx2) STEP(cx3)
#undef STEP

        cx0 = nx0; cx1 = nx1; cx2 = nx2; cx3 = nx3;
    }

    // ---- epilogue: y = h_T @ W_out^T + b_out ----
    __syncthreads();
    if (tid < WAVES_PER_BLOCK * ODIM) {   // 32 threads
        const int r = tid >> 3;
        const int o = tid & 7;
        float acc = b_out[o];
#pragma unroll
        for (int j = 0; j < HDIM; ++j)
            acc = fmaf(hsh[r][j], W_out[o * HDIM + j], acc);
        out[((long long)blockIdx.x * WAVES_PER_BLOCK + r) * ODIM + o] = acc;
    }
}

extern "C" void kernel_launch(void* const* d_in, const int* in_sizes, int n_in,
                              void* d_out, int out_size, void* d_ws, size_t ws_size,
                              hipStream_t stream) {
    const float* x     = (const float*)d_in[0];
    const float* W_ih  = (const float*)d_in[1];
    const float* W_hh  = (const float*)d_in[2];
    const float* b_ih  = (const float*)d_in[3];
    const float* b_hh  = (const float*)d_in[4];
    const float* W_out = (const float*)d_in[5];
    const float* b_out = (const float*)d_in[6];

    const int B = in_sizes[0] / (T_STEPS * FDIM);   // 4096
    const int grid = B / WAVES_PER_BLOCK;           // 1024 blocks = 4/CU

    rnn_scan_kernel<<<grid, 256, 0, stream>>>(
        x, W_ih, W_hh, b_ih, b_hh, W_out, b_out, (float*)d_out);
}

// Round 5
// 686.961 us; speedup vs baseline: 1.8303x; 1.0811x over previous
//
#include <hip/hip_runtime.h>

// RNN_64072322122514: B=4096, T=2048, F=8, H=32, O=8 Elman RNN, all fp32.
//   h_t = tanh(x_t @ W_ih^T + b_ih + b_hh + h_{t-1} @ W_hh^T);  y = h_T @ W_out^T + b_out
//
// R4 post-mortem (536 us hot, VALUBusy 63%, Occ 39.5%, VGPR 40): issue-bound —
// 4 waves/SIMD each spending ~100 cyc/step on ONE row, with two serialized LDS
// round trips (h write->read + ds_bpermute cross-half reduce) in the chain,
// and the x prefetch ping-pong collapsed by the compiler (VGPR=40).
// R5 restructure — rows/SIMD is fixed at 4; respend the budget:
//   - TWO rows per wave (32 lanes/row), lane q owns h-dim q and computes the
//     FULL 32-k dot (16 pk_fma) -> no bpermute, one LDS round trip per step.
//     Same per-wave instr count as R4 but serving 2 rows.
//   - 2048 waves = 2 waves/SIMD: chain-bound (~200 cyc/step) instead of
//     issue-bound (4x100): predicted ~175 us.
//   - h gather: 1 ds_write_b32 + 8 ds_read_b128 (broadcast; wave-private rows,
//     in-order LDS pipe => no barriers). Rows padded to 36 floats so the
//     wave's two rows hit disjoint bank quads.
//   - x prefetch: group-of-4 steps, A/B buffers with a 2x-unrolled group loop
//     (no buffer-copy v_movs, defeats rotation-collapse), loads pinned by
//     asm volatile memory fences.
//   - v_pk_fma_f32 forced via __builtin_elementwise_fma on float2 vectors.
//   - weights pre-scaled by 2*log2e; tanh = 1 - 2*rcp(exp2(s)+1).

typedef float v2f __attribute__((ext_vector_type(2)));

static constexpr int T_STEPS = 2048;
static constexpr int FDIM    = 8;
static constexpr int HDIM    = 32;
static constexpr int ODIM    = 8;
static constexpr int ROWS_PER_BLOCK = 8;    // 4 waves x 2 rows
static constexpr int GROUP   = 4;           // steps per prefetch group
static constexpr int NGROUP  = T_STEPS / GROUP;   // 512 (even)
static constexpr int LSTR    = 36;          // padded LDS row stride (floats)

__global__ __launch_bounds__(256, 2) void rnn_scan_kernel(
    const float* __restrict__ x,      // [B, T, F]
    const float* __restrict__ W_ih,   // [H, F]
    const float* __restrict__ W_hh,   // [H, H]
    const float* __restrict__ b_ih,   // [H]
    const float* __restrict__ b_hh,   // [H]
    const float* __restrict__ W_out,  // [O, H]
    const float* __restrict__ b_out,  // [O]
    float* __restrict__ out)          // [1, B, O]
{
    const float K = 2.8853900817779268f;  // 2*log2(e)
    const int tid  = threadIdx.x;
    const int lane = tid & 63;
    const int wave = tid >> 6;
    const int q    = lane & 31;           // h-dim owned by this lane
    const int sub  = lane >> 5;           // which of the wave's 2 rows
    const int r    = wave * 2 + sub;      // row within block
    const long long b = (long long)blockIdx.x * ROWS_PER_BLOCK + r;

    __shared__ float hsh[ROWS_PER_BLOCK][LSTR];

    // ---- resident weights (full W_hh row per lane), pre-scaled by K ----
    v2f wh[16];
    const float* whr = W_hh + q * HDIM;
#pragma unroll
    for (int i = 0; i < 16; ++i) {
        v2f w; w[0] = whr[2 * i] * K; w[1] = whr[2 * i + 1] * K; wh[i] = w;
    }
    v2f wiv[4];
    const float* wir = W_ih + q * FDIM;
#pragma unroll
    for (int i = 0; i < 4; ++i) {
        v2f w; w[0] = wir[2 * i] * K; w[1] = wir[2 * i + 1] * K; wiv[i] = w;
    }
    const float bias = (b_ih[q] + b_hh[q]) * K;

    hsh[r][q] = 0.0f;   // h_0 = 0 (lane writes its own slot; wave-synchronous)

    const float4* xq = reinterpret_cast<const float4*>(x + (size_t)b * T_STEPS * FDIM);
    const float4* hp = reinterpret_cast<const float4*>(&hsh[r][0]);
    float* hw = &hsh[r][q];

#define LOADG(buf, gi)                                                         \
    {                                                                          \
        const int base = (gi) * (2 * GROUP);                                   \
        _Pragma("unroll")                                                      \
        for (int k = 0; k < 2 * GROUP; ++k) buf[k] = xq[base + k];             \
    }                                                                          \
    asm volatile("" ::: "memory");

#define STEP(xa, xb)                                                           \
    {                                                                          \
        float4 g0 = hp[0], g1 = hp[1], g2 = hp[2], g3 = hp[3];                 \
        float4 g4 = hp[4], g5 = hp[5], g6 = hp[6], g7 = hp[7];                 \
        v2f a0; a0[0] = bias; a0[1] = 0.0f;                                    \
        v2f a1 = {0.0f, 0.0f}, a2 = {0.0f, 0.0f}, a3 = {0.0f, 0.0f};           \
        v2f t;                                                                 \
        t[0] = xa.x; t[1] = xa.y;  a0 = __builtin_elementwise_fma(wiv[0], t, a0); \
        t[0] = xa.z; t[1] = xa.w;  a1 = __builtin_elementwise_fma(wiv[1], t, a1); \
        t[0] = xb.x; t[1] = xb.y;  a2 = __builtin_elementwise_fma(wiv[2], t, a2); \
        t[0] = xb.z; t[1] = xb.w;  a3 = __builtin_elementwise_fma(wiv[3], t, a3); \
        t[0] = g0.x; t[1] = g0.y;  a0 = __builtin_elementwise_fma(wh[0],  t, a0); \
        t[0] = g0.z; t[1] = g0.w;  a1 = __builtin_elementwise_fma(wh[1],  t, a1); \
        t[0] = g1.x; t[1] = g1.y;  a2 = __builtin_elementwise_fma(wh[2],  t, a2); \
        t[0] = g1.z; t[1] = g1.w;  a3 = __builtin_elementwise_fma(wh[3],  t, a3); \
        t[0] = g2.x; t[1] = g2.y;  a0 = __builtin_elementwise_fma(wh[4],  t, a0); \
        t[0] = g2.z; t[1] = g2.w;  a1 = __builtin_elementwise_fma(wh[5],  t, a1); \
        t[0] = g3.x; t[1] = g3.y;  a2 = __builtin_elementwise_fma(wh[6],  t, a2); \
        t[0] = g3.z; t[1] = g3.w;  a3 = __builtin_elementwise_fma(wh[7],  t, a3); \
        t[0] = g4.x; t[1] = g4.y;  a0 = __builtin_elementwise_fma(wh[8],  t, a0); \
        t[0] = g4.z; t[1] = g4.w;  a1 = __builtin_elementwise_fma(wh[9],  t, a1); \
        t[0] = g5.x; t[1] = g5.y;  a2 = __builtin_elementwise_fma(wh[10], t, a2); \
        t[0] = g5.z; t[1] = g5.w;  a3 = __builtin_elementwise_fma(wh[11], t, a3); \
        t[0] = g6.x; t[1] = g6.y;  a0 = __builtin_elementwise_fma(wh[12], t, a0); \
        t[0] = g6.z; t[1] = g6.w;  a1 = __builtin_elementwise_fma(wh[13], t, a1); \
        t[0] = g7.x; t[1] = g7.y;  a2 = __builtin_elementwise_fma(wh[14], t, a2); \
        t[0] = g7.z; t[1] = g7.w;  a3 = __builtin_elementwise_fma(wh[15], t, a3); \
        v2f s01 = a0 + a1, s23 = a2 + a3;                                      \
        v2f st  = s01 + s23;                                                   \
        float s = st[0] + st[1];                                               \
        float e = __builtin_amdgcn_exp2f(s);                                   \
        float rc = __builtin_amdgcn_rcpf(e + 1.0f);                            \
        *hw = fmaf(-2.0f, rc, 1.0f);                                           \
    }

#define STEPS(buf)                                                             \
    STEP(buf[0], buf[1]) STEP(buf[2], buf[3])                                  \
    STEP(buf[4], buf[5]) STEP(buf[6], buf[7])

    float4 bufA[2 * GROUP], bufB[2 * GROUP];
    LOADG(bufA, 0)

    for (int g = 0; g < NGROUP; g += 2) {
        LOADG(bufB, g + 1)
        STEPS(bufA)
        {
            const int gn = (g + 2 < NGROUP) ? (g + 2) : (NGROUP - 1);
            LOADG(bufA, gn)
        }
        STEPS(bufB)
    }
#undef STEPS
#undef STEP
#undef LOADG

    // ---- epilogue: y = h_T @ W_out^T + b_out ----
    __syncthreads();
    if (tid < ROWS_PER_BLOCK * ODIM) {   // 64 threads
        const int rr = tid >> 3;
        const int o  = tid & 7;
        float acc = b_out[o];
#pragma unroll
        for (int j = 0; j < HDIM; ++j)
            acc = fmaf(hsh[rr][j], W_out[o * HDIM + j], acc);
        out[((long long)blockIdx.x * ROWS_PER_BLOCK + rr) * ODIM + o] = acc;
    }
}

extern "C" void kernel_launch(void* const* d_in, const int* in_sizes, int n_in,
                              void* d_out, int out_size, void* d_ws, size_t ws_size,
                              hipStream_t stream) {
    const float* x     = (const float*)d_in[0];
    const float* W_ih  = (const float*)d_in[1];
    const float* W_hh  = (const float*)d_in[2];
    const float* b_ih  = (const float*)d_in[3];
    const float* b_hh  = (const float*)d_in[4];
    const float* W_out = (const float*)d_in[5];
    const float* b_out = (const float*)d_in[6];

    const int B = in_sizes[0] / (T_STEPS * FDIM);   // 4096
    const int grid = B / ROWS_PER_BLOCK;            // 512 blocks = 2/CU

    rnn_scan_kernel<<<grid, 256, 0, stream>>>(
        x, W_ih, W_hh, b_ih, b_hh, W_out, b_out, (float*)d_out);
}

// Round 6
// 643.125 us; speedup vs baseline: 1.9550x; 1.0682x over previous
//
#include <hip/hip_runtime.h>

// RNN_64072322122514: B=4096, T=2048, F=8, H=32, O=8 Elman RNN, all fp32 I/O.
//   h_t = tanh(x_t @ W_ih^T + b_ih + b_hh + h_{t-1} @ W_hh^T);  y = h_T @ W_out^T + b_out
//
// R5 post-mortem: LDS-return-BW-bound. Model: 8 waves/CU x 8 ds_read_b128
// (1 KB each, 128 B/clk/CU) = 528 clk/CU-step ~= measured 563 (481 us). The
// h all-gather's 32x amplification pays full freight on the LDS return path.
// R6: cut gather bytes 4x:
//   - h and W_hh in fp16 (v_dot2_f32_f16, fp32 accumulate). fp16 rel err
//     2^-11 -> steady-state h err <1e-3 (bf16 would random-walk ~4e-3/step).
//   - 2-way k-split: lane (dim-pair g, half c) reads 16 fp16 = 32 B
//     (2 ds_read_b128); cross-half combine via 1 ds_swizzle xor16 per dim.
//     Each lane then computes only ONE tanh (partner does the other dim) --
//     halves the quarter-rate exp/rcp load too.
//   - LDS/CU-step ~168 clk vs R5's 528; SIMD issue ~170 -> balanced.
//   - x read split by f-half: lane reads ONE float4/step; GROUP=4 A/B
//     prefetch with asm memory-clobber pinning (R5 scheme, worked).
//   - weights pre-scaled by 2*log2e; tanh = 1 - 2*rcp(exp2(s)+1).

typedef float v2f __attribute__((ext_vector_type(2)));
typedef _Float16 h2v __attribute__((ext_vector_type(2)));

static constexpr int T_STEPS = 2048;
static constexpr int FDIM    = 8;
static constexpr int HDIM    = 32;
static constexpr int ODIM    = 8;
static constexpr int ROWS_PER_BLOCK = 8;    // 4 waves x 2 rows
static constexpr int GROUP   = 4;           // steps per prefetch group
static constexpr int NGROUP  = T_STEPS / GROUP;   // 512 (even)
static constexpr int LSTR    = 40;          // fp16 LDS row stride (80 B, 16B-aligned)

__device__ __forceinline__ float fdot2(h2v a, h2v b, float c) {
    return __builtin_amdgcn_fdot2(a, b, c, false);
}
__device__ __forceinline__ h2v bch(unsigned u) {
    return __builtin_bit_cast(h2v, u);
}

__global__ __launch_bounds__(256, 2) void rnn_scan_kernel(
    const float* __restrict__ x,      // [B, T, F]
    const float* __restrict__ W_ih,   // [H, F]
    const float* __restrict__ W_hh,   // [H, H]
    const float* __restrict__ b_ih,   // [H]
    const float* __restrict__ b_hh,   // [H]
    const float* __restrict__ W_out,  // [O, H]
    const float* __restrict__ b_out,  // [O]
    float* __restrict__ out)          // [1, B, O]
{
    const float K = 2.8853900817779268f;  // 2*log2(e)
    const int tid  = threadIdx.x;
    const int lane = tid & 63;
    const int wave = tid >> 6;
    const int g    = lane & 15;           // dim-pair: dims {2g, 2g+1}
    const int c    = (lane >> 4) & 1;     // k-half [16c,16c+16) and f-half [4c,4c+4)
    const int sub  = lane >> 5;           // which of the wave's 2 rows
    const int r    = wave * 2 + sub;      // row within block
    const long long b = (long long)blockIdx.x * ROWS_PER_BLOCK + r;
    const int d0 = 2 * g, d1 = 2 * g + 1;

    __shared__ _Float16 hsh[ROWS_PER_BLOCK][LSTR];

    // ---- resident weights (fp16, pre-scaled by K) ----
    h2v wA[8], wB[8];     // dims d0/d1 over k in [16c, 16c+16)
    const float* whr0 = W_hh + d0 * HDIM + 16 * c;
    const float* whr1 = W_hh + d1 * HDIM + 16 * c;
#pragma unroll
    for (int j = 0; j < 8; ++j) {
        h2v wa; wa[0] = (_Float16)(whr0[2 * j] * K); wa[1] = (_Float16)(whr0[2 * j + 1] * K);
        wA[j] = wa;
        h2v wb; wb[0] = (_Float16)(whr1[2 * j] * K); wb[1] = (_Float16)(whr1[2 * j + 1] * K);
        wB[j] = wb;
    }
    v2f wiv[4];           // xp weights (fp32) for f in [4c, 4c+4)
#pragma unroll
    for (int f = 0; f < 4; ++f) {
        v2f w; w[0] = W_ih[d0 * FDIM + 4 * c + f] * K;
               w[1] = W_ih[d1 * FDIM + 4 * c + f] * K;
        wiv[f] = w;
    }
    v2f bias2;            // bias added once (by the c=0 half)
    bias2[0] = c ? 0.0f : (b_ih[d0] + b_hh[d0]) * K;
    bias2[1] = c ? 0.0f : (b_ih[d1] + b_hh[d1]) * K;

    hsh[r][2 * g + c] = (_Float16)0.0f;   // h_0 = 0 (covers all 32 dims)

    const float4* xq = reinterpret_cast<const float4*>(x + (size_t)b * T_STEPS * FDIM);
    const uint4* hq = reinterpret_cast<const uint4*>(
        reinterpret_cast<const char*>(&hsh[r][0]) + 32 * c);
    _Float16* hw = &hsh[r][2 * g + c];

#define LOADG(buf, gi)                                                         \
    {                                                                          \
        const int base = (gi) * (2 * GROUP) + c;                               \
        _Pragma("unroll")                                                      \
        for (int k = 0; k < GROUP; ++k) buf[k] = xq[base + 2 * k];             \
    }                                                                          \
    asm volatile("" ::: "memory");

#define STEP(xr)                                                               \
    {                                                                          \
        uint4 u0 = hq[0], u1 = hq[1];                                          \
        float c00 = 0.0f, c01 = 0.0f, c10 = 0.0f, c11 = 0.0f;                  \
        c00 = fdot2(wA[0], bch(u0.x), c00);  c10 = fdot2(wB[0], bch(u0.x), c10); \
        c01 = fdot2(wA[4], bch(u1.x), c01);  c11 = fdot2(wB[4], bch(u1.x), c11); \
        c00 = fdot2(wA[1], bch(u0.y), c00);  c10 = fdot2(wB[1], bch(u0.y), c10); \
        c01 = fdot2(wA[5], bch(u1.y), c01);  c11 = fdot2(wB[5], bch(u1.y), c11); \
        c00 = fdot2(wA[2], bch(u0.z), c00);  c10 = fdot2(wB[2], bch(u0.z), c10); \
        c01 = fdot2(wA[6], bch(u1.z), c01);  c11 = fdot2(wB[6], bch(u1.z), c11); \
        c00 = fdot2(wA[3], bch(u0.w), c00);  c10 = fdot2(wB[3], bch(u0.w), c10); \
        c01 = fdot2(wA[7], bch(u1.w), c01);  c11 = fdot2(wB[7], bch(u1.w), c11); \
        v2f a = bias2;                                                         \
        v2f t;                                                                 \
        t[0] = xr.x; t[1] = xr.x;  a = __builtin_elementwise_fma(wiv[0], t, a); \
        t[0] = xr.y; t[1] = xr.y;  a = __builtin_elementwise_fma(wiv[1], t, a); \
        t[0] = xr.z; t[1] = xr.z;  a = __builtin_elementwise_fma(wiv[2], t, a); \
        t[0] = xr.w; t[1] = xr.w;  a = __builtin_elementwise_fma(wiv[3], t, a); \
        v2f dotv; dotv[0] = c00 + c01; dotv[1] = c10 + c11;                    \
        v2f s2 = a + dotv;                                                     \
        float o0 = __int_as_float(__builtin_amdgcn_ds_swizzle(                 \
                       __float_as_int(s2[0]), 0x401f));                        \
        float o1 = __int_as_float(__builtin_amdgcn_ds_swizzle(                 \
                       __float_as_int(s2[1]), 0x401f));                        \
        float s = c ? (s2[1] + o1) : (s2[0] + o0);                             \
        float e = __builtin_amdgcn_exp2f(s);                                   \
        float rc = __builtin_amdgcn_rcpf(e + 1.0f);                            \
        *hw = (_Float16)fmaf(-2.0f, rc, 1.0f);                                 \
    }

#define STEPS(buf) STEP(buf[0]) STEP(buf[1]) STEP(buf[2]) STEP(buf[3])

    float4 bufA[GROUP], bufB[GROUP];
    LOADG(bufA, 0)

    for (int gi = 0; gi < NGROUP; gi += 2) {
        LOADG(bufB, gi + 1)
        STEPS(bufA)
        {
            const int gn = (gi + 2 < NGROUP) ? (gi + 2) : (NGROUP - 1);
            LOADG(bufA, gn)
        }
        STEPS(bufB)
    }
#undef STEPS
#undef STEP
#undef LOADG

    // ---- epilogue: y = h_T @ W_out^T + b_out ----
    __syncthreads();
    if (tid < ROWS_PER_BLOCK * ODIM) {   // 64 threads
        const int rr = tid >> 3;
        const int o  = tid & 7;
        float acc = b_out[o];
#pragma unroll
        for (int j = 0; j < HDIM; ++j)
            acc = fmaf((float)hsh[rr][j], W_out[o * HDIM + j], acc);
        out[((long long)blockIdx.x * ROWS_PER_BLOCK + rr) * ODIM + o] = acc;
    }
}

extern "C" void kernel_launch(void* const* d_in, const int* in_sizes, int n_in,
                              void* d_out, int out_size, void* d_ws, size_t ws_size,
                              hipStream_t stream) {
    const float* x     = (const float*)d_in[0];
    const float* W_ih  = (const float*)d_in[1];
    const float* W_hh  = (const float*)d_in[2];
    const float* b_ih  = (const float*)d_in[3];
    const float* b_hh  = (const float*)d_in[4];
    const float* W_out = (const float*)d_in[5];
    const float* b_out = (const float*)d_in[6];

    const int B = in_sizes[0] / (T_STEPS * FDIM);   // 4096
    const int grid = B / ROWS_PER_BLOCK;            // 512 blocks = 2/CU

    rnn_scan_kernel<<<grid, 256, 0, stream>>>(
        x, W_ih, W_hh, b_ih, b_hh, W_out, b_out, (float*)d_out);
}